// Round 13
// baseline (174.847 us; speedup 1.0000x reference)
//
#include <hip/hip_runtime.h>
#include <hip/hip_bf16.h>
#include <math.h>

typedef short bf16x8 __attribute__((ext_vector_type(8)));
typedef float f32x4 __attribute__((ext_vector_type(4)));
typedef unsigned short u16;
typedef unsigned int u32;

#define BATCH 128
#define NE 256
#define NO 256
#define NT 32
#define NH 768
#define NP 256
#define NKT 12                      // 768 / 64 K-tiles
#define INV_TEMP 14.285714285714285714f

__device__ __forceinline__ u16 f2bf(float f) {
    union { float f; u32 u; } v; v.f = f;
    u32 u = v.u;
    u += 0x7fffu + ((u >> 16) & 1u);   // round-to-nearest-even
    return (u16)(u >> 16);
}

__device__ __forceinline__ void gload16(const void* g, void* l) {
    __builtin_amdgcn_global_load_lds(
        (const __attribute__((address_space(1))) unsigned int*)g,
        (__attribute__((address_space(3))) unsigned int*)l,
        16, 0, 0);
}

// LDS fragment read with XOR swizzle (row stride 128 B)
__device__ __forceinline__ bf16x8 ldfrag(const char* base, int row, int kb, int rs) {
    return *(const bf16x8*)(base + row * 128 + (kb ^ rs));
}

#define PH_SYNC_IN()                                          \
    __builtin_amdgcn_s_barrier();                             \
    asm volatile("s_waitcnt lgkmcnt(0)" ::: "memory");        \
    __builtin_amdgcn_sched_barrier(0);                        \
    __builtin_amdgcn_s_setprio(1);

#define PH_SYNC_OUT()                                         \
    __builtin_amdgcn_s_setprio(0);                            \
    __builtin_amdgcn_s_barrier();

// ---------------- merged prep (r9 shape): activations->bf16 (w/ gather) + 4
// weight transposes. One chunk per thread (13.8k blocks) — fastest measured.
#define PREP_ACONV_OP_BLOCKS   12288   // 32768 rows * 96 chunks / 256
#define PREP_ACONV_EN_BLOCKS   1536    // 4096 rows * 96 chunks / 256
#define PREP_WT1_TILES         576     // (768/32)*(768/32)
#define PREP_WT2_TILES         192     // (256/32)*(768/32)
#define PREP_TOTAL (PREP_ACONV_OP_BLOCKS + PREP_ACONV_EN_BLOCKS + 2*PREP_WT1_TILES + 2*PREP_WT2_TILES)

__device__ __forceinline__ void aconv_body(const float* __restrict__ A,
                                           const int* __restrict__ pairs,
                                           u16* __restrict__ out, int gid) {
    int row = gid / (NH / 8);
    int q = gid - row * (NH / 8);
    size_t srow;
    if (pairs) {
        int e = pairs[2 * row];
        int b = row >> 5;            // T = 32
        srow = (size_t)(b * NE + e);
    } else {
        srow = (size_t)row;
    }
    const float* p = A + srow * NH + q * 8;
    float4 a0 = *(const float4*)(p);
    float4 a1 = *(const float4*)(p + 4);
    u16 ua[8];
    ua[0] = f2bf(a0.x); ua[1] = f2bf(a0.y); ua[2] = f2bf(a0.z); ua[3] = f2bf(a0.w);
    ua[4] = f2bf(a1.x); ua[5] = f2bf(a1.y); ua[6] = f2bf(a1.z); ua[7] = f2bf(a1.w);
    *(uint4*)(out + (size_t)row * NH + q * 8) = *(uint4*)ua;
}

__global__ __launch_bounds__(256) void prep_kernel(
        const float* __restrict__ opi, const float* __restrict__ ent,
        const int* __restrict__ prs,
        const float* __restrict__ oW1, const float* __restrict__ eW1,
        const float* __restrict__ oW2, const float* __restrict__ eW2,
        u16* __restrict__ A_op, u16* __restrict__ A_en,
        u16* __restrict__ oW1T, u16* __restrict__ eW1T,
        u16* __restrict__ oW2T, u16* __restrict__ eW2T) {
    __shared__ float ttile[32][33];
    const int bid = blockIdx.x;
    const int tid = threadIdx.x;
    if (bid < PREP_ACONV_OP_BLOCKS) {
        aconv_body(opi, nullptr, A_op, bid * 256 + tid);
        return;
    }
    if (bid < PREP_ACONV_OP_BLOCKS + PREP_ACONV_EN_BLOCKS) {
        aconv_body(ent, prs, A_en, (bid - PREP_ACONV_OP_BLOCKS) * 256 + tid);
        return;
    }
    // weight transpose tiles
    int tb = bid - (PREP_ACONV_OP_BLOCKS + PREP_ACONV_EN_BLOCKS);
    const float* W; u16* WT; int N;
    if (tb < PREP_WT1_TILES)                     { W = oW1; WT = oW1T; N = NH; }
    else if ((tb -= PREP_WT1_TILES) < PREP_WT1_TILES) { W = eW1; WT = eW1T; N = NH; }
    else if ((tb -= PREP_WT1_TILES) < PREP_WT2_TILES) { W = oW2; WT = oW2T; N = NP; }
    else { tb -= PREP_WT2_TILES;                   W = eW2; WT = eW2T; N = NP; }
    const int nk = NH / 32;                       // 24 tiles along k
    const int tn = tb / nk, tk = tb - tn * nk;
    const int k0 = tk * 32, n0 = tn * 32;
    const int tx = tid & 31, ty = tid >> 5;       // ty 0..7
    #pragma unroll
    for (int i = 0; i < 4; ++i)
        ttile[ty + 8 * i][tx] = W[(size_t)(k0 + ty + 8 * i) * N + n0 + tx];
    __syncthreads();
    #pragma unroll
    for (int i = 0; i < 4; ++i)
        WT[(size_t)(n0 + ty + 8 * i) * NH + k0 + tx] = f2bf(ttile[tx][ty + 8 * i]);
}

// ---------------- GEMM1: h = relu(A @ W1 + b1), merged opinion+entity --------
// 128x128 tile, BK=64, 256 thr (4 waves 2Mx2N). A-fragments are read DIRECTLY
// from global into registers (each frag instr = 16 fully-used 64B lines, same
// line count as coalesced staging; A panels L2/L3-hot) — this halves LDS
// traffic (was 96 KB/block-tile, now 48 KB: B stage+read only). A-frags are
// double-buffered in regs (aC/aN), prefetched in phase 0 with a full tile of
// flight. B path + 2-phase cadence identical to the r9 champion. LDS = 32 KB.
#define G1_STAGE_B(t_, d_)                                                       \
  { _Pragma("unroll")                                                            \
    for (int i_ = 0; i_ < 4; ++i_)                                               \
      gload16((const char*)(bg + (size_t)(i_ * 32 + srow) * NH + (t_) * 64) + sswz, \
              (char*)&Bs[d_][0] + i_ * 4096 + tid * 16); }

#define G1_PREF_A(dst_, t_)                                                      \
  { _Pragma("unroll")                                                            \
    for (int mf_ = 0; mf_ < 4; ++mf_)                                            \
      _Pragma("unroll")                                                          \
      for (int ks_ = 0; ks_ < 2; ++ks_)                                          \
        dst_[mf_][ks_] = *(const bf16x8*)(aLane + (size_t)mf_ * 16 * NH +        \
                                          (t_) * 64 + ks_ * 32); }

#define G1_TILE(t_, AC_, AN_, d_)                                                \
  {                                                                              \
    const char* Bb = (const char*)&Bs[d_][0];                                    \
    bf16x8 bF[4];                                                                \
    /* phase 0: B ks0 frags ; prefetch A(t+1) regs + stage B(t+1) */             \
    _Pragma("unroll")                                                            \
    for (int nf = 0; nf < 4; ++nf) bF[nf] = ldfrag(Bb, wn * 64 + nf * 16 + lr, kq, rs); \
    if ((t_) < NKT - 1) { G1_PREF_A(AN_, (t_) + 1); G1_STAGE_B((t_) + 1, (d_) ^ 1); } \
    PH_SYNC_IN();                                                                \
    _Pragma("unroll")                                                            \
    for (int mf = 0; mf < 4; ++mf)                                               \
        _Pragma("unroll")                                                        \
        for (int nf = 0; nf < 4; ++nf)                                           \
            acc[mf][nf] = __builtin_amdgcn_mfma_f32_16x16x32_bf16(AC_[mf][0], bF[nf], acc[mf][nf], 0, 0, 0); \
    PH_SYNC_OUT();                                                               \
    /* phase 1: B ks1 frags ; vmcnt(0) at tile end (long flight) */              \
    _Pragma("unroll")                                                            \
    for (int nf = 0; nf < 4; ++nf) bF[nf] = ldfrag(Bb, wn * 64 + nf * 16 + lr, 64 + kq, rs); \
    PH_SYNC_IN();                                                                \
    _Pragma("unroll")                                                            \
    for (int mf = 0; mf < 4; ++mf)                                               \
        _Pragma("unroll")                                                        \
        for (int nf = 0; nf < 4; ++nf)                                           \
            acc[mf][nf] = __builtin_amdgcn_mfma_f32_16x16x32_bf16(AC_[mf][1], bF[nf], acc[mf][nf], 0, 0, 0); \
    __builtin_amdgcn_s_setprio(0);                                               \
    asm volatile("s_waitcnt vmcnt(0)" ::: "memory");                             \
    __builtin_amdgcn_sched_barrier(0);                                           \
    __builtin_amdgcn_s_barrier();                                                \
  }

__launch_bounds__(256, 2)
__global__ void gemm1_kernel(const u16* __restrict__ A_op, const u16* __restrict__ A_en,
                             const u16* __restrict__ oW1T, const u16* __restrict__ eW1T,
                             const float* __restrict__ ob1, const float* __restrict__ eb1,
                             u16* __restrict__ Hop, u16* __restrict__ Hen) {
    __shared__ u16 Bs[2][128 * 64];   // 32 KB total
    const int cpx = gridDim.x >> 3;
    const int wg = (blockIdx.x & 7) * cpx + (blockIdx.x >> 3);
    const bool isent = wg >= 1536;                // opinion: 1536 blocks, entity: 192
    const int wgl = isent ? wg - 1536 : wg;
    const int mt = wgl / 6;                       // NH/128 = 6 col tiles
    const int nt = wgl - mt * 6;
    const u16* WT = isent ? eW1T : oW1T;
    const float* bias = isent ? eb1 : ob1;
    u16* outH = isent ? Hen : Hop;
    const u16* Abase = isent ? A_en : A_op;

    const int tid = threadIdx.x;
    const int lane = tid & 63;
    const int w = tid >> 6;
    const int wm = w >> 1, wn = w & 1;            // 2M x 2N wave grid
    const int lr = lane & 15;
    const int kq = (lane >> 4) << 4;
    const int rs = (lr & 7) << 4;

    const int srow = tid >> 3;                    // 0..31
    const int sswz = ((tid & 7) * 16) ^ ((srow & 7) << 4);
    const u16* bg = WT + (size_t)(nt * 128) * NH;
    // A-direct: lane's base = row (mt*128 + wm*64 + lr), elem (lane>>4)*8
    const u16* aLane = Abase + (size_t)(mt * 128 + wm * 64 + lr) * NH + ((lane >> 4) << 3);

    f32x4 acc[4][4] = {};
    bf16x8 aC[4][2], aN[4][2];

    G1_PREF_A(aC, 0);
    G1_STAGE_B(0, 0);
    asm volatile("s_waitcnt vmcnt(0)" ::: "memory");
    __builtin_amdgcn_s_barrier();

    #pragma unroll
    for (int tt = 0; tt < NKT; tt += 2) {
        G1_TILE(tt, aC, aN, 0);
        G1_TILE(tt + 1, aN, aC, 1);
    }

    const int r0 = (lane >> 4) << 2;
    float bv[4];
    #pragma unroll
    for (int nf = 0; nf < 4; ++nf) bv[nf] = bias[nt * 128 + wn * 64 + nf * 16 + lr];
    #pragma unroll
    for (int mf = 0; mf < 4; ++mf) {
        #pragma unroll
        for (int r = 0; r < 4; ++r) {
            const int row = mt * 128 + wm * 64 + mf * 16 + r0 + r;
            u16* orow = outH + (size_t)row * NH + nt * 128 + wn * 64 + lr;
            #pragma unroll
            for (int nf = 0; nf < 4; ++nf) {
                float v = acc[mf][nf][r] + bv[nf];
                orow[nf * 16] = f2bf(fmaxf(v, 0.0f));
            }
        }
    }
}

// ---------------- GEMM2 + L2 normalize (merged opinion+entity) ---------------
// 64x256 tile, BK=64, 256 thr (4 waves side-by-side in N), 80 KB LDS ->
// 2 blocks/CU. r9's 2-phase loop (stage both in phase 0). Unchanged.
#define G2_STAGE_A(t_, d_)                                                       \
  { _Pragma("unroll")                                                            \
    for (int i_ = 0; i_ < 2; ++i_)                                               \
      gload16((const char*)(ag + (size_t)(i_ * 32 + srow) * NH + (t_) * 64) + sswz, \
              (char*)&As2[d_][0] + i_ * 4096 + tid * 16); }
#define G2_STAGE_B(t_, d_)                                                       \
  { _Pragma("unroll")                                                            \
    for (int i_ = 0; i_ < 8; ++i_)                                               \
      gload16((const char*)(WT + (size_t)(i_ * 32 + srow) * NH + (t_) * 64) + sswz, \
              (char*)&Bs2[d_][0] + i_ * 4096 + tid * 16); }

__launch_bounds__(256, 2)
__global__ void gemm2norm_kernel(const u16* __restrict__ Hop, const u16* __restrict__ Hen,
                                 const u16* __restrict__ oW2T, const u16* __restrict__ eW2T,
                                 const float* __restrict__ ob2, const float* __restrict__ eb2,
                                 u16* __restrict__ opn, u16* __restrict__ eps) {
    __shared__ u16 As2[2][64 * 64];    // 16 KB (nsum aliased here after K-loop)
    __shared__ u16 Bs2[2][256 * 64];   // 64 KB
    float* nsum = (float*)&As2[0][0];  // [4][64]
    const int cpx = gridDim.x >> 3;
    const int wg = (blockIdx.x & 7) * cpx + (blockIdx.x >> 3);
    const bool isent = wg >= 512;                 // opinion: 512 blocks, entity: 64
    const int mt = isent ? wg - 512 : wg;
    const u16* Hin = isent ? Hen : Hop;
    const u16* WT = isent ? eW2T : oW2T;
    const float* bias = isent ? eb2 : ob2;
    u16* outZ = isent ? eps : opn;

    const int tid = threadIdx.x;
    const int lane = tid & 63;
    const int wn = tid >> 6;
    const int lr = lane & 15;
    const int kq = (lane >> 4) << 4;
    const int rs = (lr & 7) << 4;

    const int srow = tid >> 3;
    const int sswz = ((tid & 7) * 16) ^ ((srow & 7) << 4);
    const u16* ag = Hin + (size_t)(mt * 64) * NH;

    f32x4 acc[4][4] = {};

    G2_STAGE_A(0, 0);
    G2_STAGE_B(0, 0);
    asm volatile("s_waitcnt vmcnt(0)" ::: "memory");
    __builtin_amdgcn_s_barrier();

    for (int t = 0; t < NKT; ++t) {
        const int d = t & 1;
        const char* Ab = (const char*)&As2[d][0];
        const char* Bb = (const char*)&Bs2[d][0];
        bf16x8 aF[4], bF[4];
        // ---- phase 0: all frags ks0 ; stage A(t+1) AND B(t+1)
        #pragma unroll
        for (int mf = 0; mf < 4; ++mf) aF[mf] = ldfrag(Ab, mf * 16 + lr, kq, rs);
        #pragma unroll
        for (int nf = 0; nf < 4; ++nf) bF[nf] = ldfrag(Bb, wn * 64 + nf * 16 + lr, kq, rs);
        if (t < NKT - 1) { G2_STAGE_A(t + 1, d ^ 1); G2_STAGE_B(t + 1, d ^ 1); }
        PH_SYNC_IN();
        #pragma unroll
        for (int mf = 0; mf < 4; ++mf)
            #pragma unroll
            for (int nf = 0; nf < 4; ++nf)
                acc[mf][nf] = __builtin_amdgcn_mfma_f32_16x16x32_bf16(aF[mf], bF[nf], acc[mf][nf], 0, 0, 0);
        PH_SYNC_OUT();
        // ---- phase 1: all frags ks1 ; vmcnt(0) at tile end
        #pragma unroll
        for (int mf = 0; mf < 4; ++mf) aF[mf] = ldfrag(Ab, mf * 16 + lr, 64 + kq, rs);
        #pragma unroll
        for (int nf = 0; nf < 4; ++nf) bF[nf] = ldfrag(Bb, wn * 64 + nf * 16 + lr, 64 + kq, rs);
        PH_SYNC_IN();
        #pragma unroll
        for (int mf = 0; mf < 4; ++mf)
            #pragma unroll
            for (int nf = 0; nf < 4; ++nf)
                acc[mf][nf] = __builtin_amdgcn_mfma_f32_16x16x32_bf16(aF[mf], bF[nf], acc[mf][nf], 0, 0, 0);
        __builtin_amdgcn_s_setprio(0);
        asm volatile("s_waitcnt vmcnt(0)" ::: "memory");
        __builtin_amdgcn_sched_barrier(0);
        __builtin_amdgcn_s_barrier();
    }

    // bias + row sum-of-squares
    const int cc = wn * 64 + lr;
    #pragma unroll
    for (int nf = 0; nf < 4; ++nf) {
        const float bvv = bias[cc + nf * 16];
        #pragma unroll
        for (int mf = 0; mf < 4; ++mf)
            #pragma unroll
            for (int r = 0; r < 4; ++r)
                acc[mf][nf][r] += bvv;
    }
    float rsq[4][4];
    #pragma unroll
    for (int mf = 0; mf < 4; ++mf)
        #pragma unroll
        for (int r = 0; r < 4; ++r) {
            float s = 0.f;
            #pragma unroll
            for (int nf = 0; nf < 4; ++nf) s += acc[mf][nf][r] * acc[mf][nf][r];
            rsq[mf][r] = s;
        }
    #pragma unroll
    for (int mask = 1; mask <= 8; mask <<= 1)
        #pragma unroll
        for (int mf = 0; mf < 4; ++mf)
            #pragma unroll
            for (int r = 0; r < 4; ++r)
                rsq[mf][r] += __shfl_xor(rsq[mf][r], mask);
    const int r0 = (lane >> 4) << 2;
    __syncthreads();                    // As2 reads all done; safe to alias nsum
    if (lr == 0) {
        #pragma unroll
        for (int mf = 0; mf < 4; ++mf)
            #pragma unroll
            for (int r = 0; r < 4; ++r)
                nsum[wn * 64 + mf * 16 + r0 + r] = rsq[mf][r];
    }
    __syncthreads();
    #pragma unroll
    for (int mf = 0; mf < 4; ++mf) {
        #pragma unroll
        for (int r = 0; r < 4; ++r) {
            const int row = mf * 16 + r0 + r;
            const float tot = nsum[row] + nsum[64 + row] + nsum[128 + row] + nsum[192 + row];
            const float inv = 1.0f / fmaxf(sqrtf(tot), 1e-12f);
            u16* orow = outZ + (size_t)(mt * 64 + row) * NP + cc;
            #pragma unroll
            for (int nf = 0; nf < 4; ++nf)
                orow[nf * 16] = f2bf(acc[mf][nf][r] * inv);
        }
    }
}

// ---------------- score: 2 blocks per batch; wave-parallel single-pass softmax
__launch_bounds__(256)
__global__ void score_kernel(const u16* __restrict__ epsel, const u16* __restrict__ opn,
                             const int* __restrict__ pairs, float* __restrict__ partials) {
    __shared__ u16 Asx[16][264];
    __shared__ float simbuf[16][257];
    __shared__ float red[16];
    const int b = blockIdx.x >> 1;
    const int half = blockIdx.x & 1;
    const int rbase = half * 16;
    const int tid = threadIdx.x;
    const int lane = tid & 63;
    const int w = tid >> 6;
    {
        const int row = tid >> 4, q = tid & 15;   // 16 threads per row, 16 elems each
        const u16* p = epsel + ((size_t)(b * NT + rbase + row)) * NP + q * 16;
        *(uint4*)&Asx[row][q * 16 + 0] = *(const uint4*)(p + 0);
        *(uint4*)&Asx[row][q * 16 + 8] = *(const uint4*)(p + 8);
    }
    __syncthreads();
    f32x4 acc[4] = {};
    const u16* opb = opn + (size_t)b * NO * NP;
    const int kq = (lane >> 4) << 3;
    for (int kk = 0; kk < NP; kk += 32) {
        bf16x8 af = *(const bf16x8*)&Asx[lane & 15][kk + kq];
        #pragma unroll
        for (int n = 0; n < 4; ++n) {
            bf16x8 bfr = *(const bf16x8*)(opb + (size_t)(w * 64 + n * 16 + (lane & 15)) * NP + kk + kq);
            acc[n] = __builtin_amdgcn_mfma_f32_16x16x32_bf16(af, bfr, acc[n], 0, 0, 0);
        }
    }
    const int r0 = (lane >> 4) << 2;
    #pragma unroll
    for (int n = 0; n < 4; ++n)
        #pragma unroll
        for (int r = 0; r < 4; ++r)
            simbuf[r0 + r][w * 64 + n * 16 + (lane & 15)] = acc[n][r] * INV_TEMP;
    __syncthreads();
    {
        const int row = tid >> 4, sub = tid & 15;
        float s = 0.f;
        #pragma unroll 4
        for (int j = sub; j < NO; j += 16) s += __expf(simbuf[row][j]);
        s += __shfl_xor(s, 1);
        s += __shfl_xor(s, 2);
        s += __shfl_xor(s, 4);
        s += __shfl_xor(s, 8);
        if (sub == 0) {
            const int o = pairs[(b * NT + rbase + row) * 2 + 1];
            red[row] = logf(s) - simbuf[row][o];
        }
    }
    __syncthreads();
    if (tid == 0) {
        float s = 0.f;
        #pragma unroll
        for (int t = 0; t < 16; ++t) s += red[t];
        partials[blockIdx.x] = s;
    }
}

__global__ void reduce_kernel(const float* __restrict__ partials, float* __restrict__ out) {
    const int tid = threadIdx.x;              // 256
    float v = partials[tid];
    #pragma unroll
    for (int m = 1; m <= 32; m <<= 1) v += __shfl_xor(v, m);
    __shared__ float s[4];
    if ((tid & 63) == 0) s[tid >> 6] = v;
    __syncthreads();
    if (tid == 0) out[0] = (s[0] + s[1] + s[2] + s[3]) / (float)(BATCH * NT);
}

extern "C" void kernel_launch(void* const* d_in, const int* in_sizes, int n_in,
                              void* d_out, int out_size, void* d_ws, size_t ws_size,
                              hipStream_t stream) {
    const float* ent  = (const float*)d_in[0];
    const float* opi  = (const float*)d_in[1];
    const int*   prs  = (const int*)d_in[2];
    const float* eW1  = (const float*)d_in[3];
    const float* eb1  = (const float*)d_in[4];
    const float* eW2  = (const float*)d_in[5];
    const float* eb2  = (const float*)d_in[6];
    const float* oW1  = (const float*)d_in[7];
    const float* ob1  = (const float*)d_in[8];
    const float* oW2  = (const float*)d_in[9];
    const float* ob2  = (const float*)d_in[10];
    float* out = (float*)d_out;

    char* ws = (char*)d_ws;
    size_t off = 0;
    auto alloc = [&](size_t bytes) {
        void* p = ws + off;
        off += (bytes + 255) & ~(size_t)255;
        return p;
    };
    u16* oW1T = (u16*)alloc((size_t)NH * NH * 2);
    u16* eW1T = (u16*)alloc((size_t)NH * NH * 2);
    u16* oW2T = (u16*)alloc((size_t)NP * NH * 2);
    u16* eW2T = (u16*)alloc((size_t)NP * NH * 2);
    u16* A_op = (u16*)alloc((size_t)BATCH * NO * NH * 2);
    u16* A_en = (u16*)alloc((size_t)BATCH * NT * NH * 2);
    u16* h_op = (u16*)alloc((size_t)BATCH * NO * NH * 2);
    u16* h_en = (u16*)alloc((size_t)BATCH * NT * NH * 2);
    u16* op_n = (u16*)alloc((size_t)BATCH * NO * NP * 2);
    u16* ep_s = (u16*)alloc((size_t)BATCH * NT * NP * 2);
    float* partials = (float*)alloc(2 * BATCH * sizeof(float));
    (void)ws_size; (void)in_sizes; (void)n_in; (void)out_size;

    // merged prep: activations bf16 (+ entity gather) + 4 weight transposes
    prep_kernel<<<PREP_TOTAL, 256, 0, stream>>>(opi, ent, prs, oW1, eW1, oW2, eW2,
                                                A_op, A_en, oW1T, eW1T, oW2T, eW2T);

    // encoder layer 1 (relu): opinion 1536 + entity 192 = 1728 blocks (%8==0)
    gemm1_kernel<<<1728, 256, 0, stream>>>(A_op, A_en, oW1T, eW1T, ob1, eb1, h_op, h_en);

    // encoder layer 2 + normalize: opinion 512 + entity 64 = 576 blocks (%8==0)
    gemm2norm_kernel<<<576, 256, 0, stream>>>(h_op, h_en, oW2T, eW2T, ob2, eb2, op_n, ep_s);

    // similarity rows + InfoNCE partials (2 blocks per batch)
    score_kernel<<<2 * BATCH, 256, 0, stream>>>(ep_s, op_n, prs, partials);
    reduce_kernel<<<1, 256, 0, stream>>>(partials, out);
}

// Round 14
// 126.489 us; speedup vs baseline: 1.3823x; 1.3823x over previous
//
#include <hip/hip_runtime.h>
#include <hip/hip_bf16.h>
#include <math.h>

typedef short bf16x8 __attribute__((ext_vector_type(8)));
typedef float f32x4 __attribute__((ext_vector_type(4)));
typedef unsigned short u16;
typedef unsigned int u32;

#define BATCH 128
#define NE 256
#define NO 256
#define NT 32
#define NH 768
#define NP 256
#define NKT 12                      // 768 / 64 K-tiles
#define INV_TEMP 14.285714285714285714f

__device__ __forceinline__ u16 f2bf(float f) {
    union { float f; u32 u; } v; v.f = f;
    u32 u = v.u;
    u += 0x7fffu + ((u >> 16) & 1u);   // round-to-nearest-even
    return (u16)(u >> 16);
}

__device__ __forceinline__ void gload16(const void* g, void* l) {
    __builtin_amdgcn_global_load_lds(
        (const __attribute__((address_space(1))) unsigned int*)g,
        (__attribute__((address_space(3))) unsigned int*)l,
        16, 0, 0);
}

// LDS fragment read with XOR swizzle (row stride 128 B)
__device__ __forceinline__ bf16x8 ldfrag(const char* base, int row, int kb, int rs) {
    return *(const bf16x8*)(base + row * 128 + (kb ^ rs));
}

#define PH_SYNC_IN()                                          \
    __builtin_amdgcn_s_barrier();                             \
    asm volatile("s_waitcnt lgkmcnt(0)" ::: "memory");        \
    __builtin_amdgcn_sched_barrier(0);                        \
    __builtin_amdgcn_s_setprio(1);

#define PH_SYNC_OUT()                                         \
    __builtin_amdgcn_s_setprio(0);                            \
    __builtin_amdgcn_s_barrier();

// ---------------- merged prep (r9 shape): activations->bf16 (w/ gather) + 4
// weight transposes. One chunk per thread — fastest measured shape.
#define PREP_ACONV_OP_BLOCKS   12288   // 32768 rows * 96 chunks / 256
#define PREP_ACONV_EN_BLOCKS   1536    // 4096 rows * 96 chunks / 256
#define PREP_WT1_TILES         576     // (768/32)*(768/32)
#define PREP_WT2_TILES         192     // (256/32)*(768/32)
#define PREP_TOTAL (PREP_ACONV_OP_BLOCKS + PREP_ACONV_EN_BLOCKS + 2*PREP_WT1_TILES + 2*PREP_WT2_TILES)

__device__ __forceinline__ void aconv_body(const float* __restrict__ A,
                                           const int* __restrict__ pairs,
                                           u16* __restrict__ out, int gid) {
    int row = gid / (NH / 8);
    int q = gid - row * (NH / 8);
    size_t srow;
    if (pairs) {
        int e = pairs[2 * row];
        int b = row >> 5;            // T = 32
        srow = (size_t)(b * NE + e);
    } else {
        srow = (size_t)row;
    }
    const float* p = A + srow * NH + q * 8;
    float4 a0 = *(const float4*)(p);
    float4 a1 = *(const float4*)(p + 4);
    u16 ua[8];
    ua[0] = f2bf(a0.x); ua[1] = f2bf(a0.y); ua[2] = f2bf(a0.z); ua[3] = f2bf(a0.w);
    ua[4] = f2bf(a1.x); ua[5] = f2bf(a1.y); ua[6] = f2bf(a1.z); ua[7] = f2bf(a1.w);
    *(uint4*)(out + (size_t)row * NH + q * 8) = *(uint4*)ua;
}

__global__ __launch_bounds__(256) void prep_kernel(
        const float* __restrict__ opi, const float* __restrict__ ent,
        const int* __restrict__ prs,
        const float* __restrict__ oW1, const float* __restrict__ eW1,
        const float* __restrict__ oW2, const float* __restrict__ eW2,
        u16* __restrict__ A_op, u16* __restrict__ A_en,
        u16* __restrict__ oW1T, u16* __restrict__ eW1T,
        u16* __restrict__ oW2T, u16* __restrict__ eW2T) {
    __shared__ float ttile[32][33];
    const int bid = blockIdx.x;
    const int tid = threadIdx.x;
    if (bid < PREP_ACONV_OP_BLOCKS) {
        aconv_body(opi, nullptr, A_op, bid * 256 + tid);
        return;
    }
    if (bid < PREP_ACONV_OP_BLOCKS + PREP_ACONV_EN_BLOCKS) {
        aconv_body(ent, prs, A_en, (bid - PREP_ACONV_OP_BLOCKS) * 256 + tid);
        return;
    }
    // weight transpose tiles
    int tb = bid - (PREP_ACONV_OP_BLOCKS + PREP_ACONV_EN_BLOCKS);
    const float* W; u16* WT; int N;
    if (tb < PREP_WT1_TILES)                     { W = oW1; WT = oW1T; N = NH; }
    else if ((tb -= PREP_WT1_TILES) < PREP_WT1_TILES) { W = eW1; WT = eW1T; N = NH; }
    else if ((tb -= PREP_WT1_TILES) < PREP_WT2_TILES) { W = oW2; WT = oW2T; N = NP; }
    else { tb -= PREP_WT2_TILES;                   W = eW2; WT = eW2T; N = NP; }
    const int nk = NH / 32;                       // 24 tiles along k
    const int tn = tb / nk, tk = tb - tn * nk;
    const int k0 = tk * 32, n0 = tn * 32;
    const int tx = tid & 31, ty = tid >> 5;       // ty 0..7
    #pragma unroll
    for (int i = 0; i < 4; ++i)
        ttile[ty + 8 * i][tx] = W[(size_t)(k0 + ty + 8 * i) * N + n0 + tx];
    __syncthreads();
    #pragma unroll
    for (int i = 0; i < 4; ++i)
        WT[(size_t)(n0 + ty + 8 * i) * NH + k0 + tx] = f2bf(ttile[tx][ty + 8 * i]);
}

// ---------------- GEMM1: h = relu(A @ W1 + b1), merged opinion+entity --------
// 128x128 tile, BK=64, **512 thr (8 waves, 2M x 4N)**, 64 KB LDS dbuf ->
// 2 blocks/CU = 16 waves/CU = 4 waves/SIMD (2x the TLP of the 256-thr r9
// variant; m114: wave-level MFMA/VALU co-scheduling needs wave diversity).
// Same proven 2-phase counted cadence: stage A(t+1)+B(t+1) in phase 0,
// single vmcnt(0) at phase-1 end with a full tile of flight.
#define G1_STAGE_A(t_, d_)                                                       \
  { _Pragma("unroll")                                                            \
    for (int i_ = 0; i_ < 2; ++i_)                                               \
      gload16((const char*)(ag + (size_t)(i_ * 64 + srow) * NH + (t_) * 64) + sswz, \
              (char*)&As[d_][0] + i_ * 8192 + tid * 16); }
#define G1_STAGE_B(t_, d_)                                                       \
  { _Pragma("unroll")                                                            \
    for (int i_ = 0; i_ < 2; ++i_)                                               \
      gload16((const char*)(bg + (size_t)(i_ * 64 + srow) * NH + (t_) * 64) + sswz, \
              (char*)&Bs[d_][0] + i_ * 8192 + tid * 16); }

__launch_bounds__(512, 4)
__global__ void gemm1_kernel(const u16* __restrict__ A_op, const u16* __restrict__ A_en,
                             const u16* __restrict__ oW1T, const u16* __restrict__ eW1T,
                             const float* __restrict__ ob1, const float* __restrict__ eb1,
                             u16* __restrict__ Hop, u16* __restrict__ Hen) {
    __shared__ u16 As[2][128 * 64];   // 32 KB
    __shared__ u16 Bs[2][128 * 64];   // 32 KB
    const int cpx = gridDim.x >> 3;
    const int wg = (blockIdx.x & 7) * cpx + (blockIdx.x >> 3);
    const bool isent = wg >= 1536;                // opinion: 1536 blocks, entity: 192
    const int wgl = isent ? wg - 1536 : wg;
    const int mt = wgl / 6;                       // NH/128 = 6 col tiles
    const int nt = wgl - mt * 6;
    const u16* WT = isent ? eW1T : oW1T;
    const float* bias = isent ? eb1 : ob1;
    u16* outH = isent ? Hen : Hop;
    const u16* Abase = isent ? A_en : A_op;

    const int tid = threadIdx.x;
    const int lane = tid & 63;
    const int w = tid >> 6;                       // 0..7
    const int wm = w >> 2, wn = w & 3;            // 2M x 4N wave grid
    const int lr = lane & 15;
    const int kq = (lane >> 4) << 4;
    const int rs = (lr & 7) << 4;

    const int srow = tid >> 3;                    // 0..63
    const int sswz = ((tid & 7) * 16) ^ ((srow & 7) << 4);
    const u16* ag = Abase + (size_t)(mt * 128) * NH;
    const u16* bg = WT + (size_t)(nt * 128) * NH;

    f32x4 acc[4][2] = {};

    G1_STAGE_A(0, 0);
    G1_STAGE_B(0, 0);
    asm volatile("s_waitcnt vmcnt(0)" ::: "memory");
    __builtin_amdgcn_s_barrier();

    for (int t = 0; t < NKT; ++t) {
        const int d = t & 1;
        const char* Ab = (const char*)&As[d][0];
        const char* Bb = (const char*)&Bs[d][0];
        bf16x8 aF[4], bF[2];
        // ---- phase 0: all frags ks0 ; stage A(t+1) AND B(t+1)
        #pragma unroll
        for (int mf = 0; mf < 4; ++mf) aF[mf] = ldfrag(Ab, wm * 64 + mf * 16 + lr, kq, rs);
        #pragma unroll
        for (int nf = 0; nf < 2; ++nf) bF[nf] = ldfrag(Bb, wn * 32 + nf * 16 + lr, kq, rs);
        if (t < NKT - 1) { G1_STAGE_A(t + 1, d ^ 1); G1_STAGE_B(t + 1, d ^ 1); }
        PH_SYNC_IN();
        #pragma unroll
        for (int mf = 0; mf < 4; ++mf)
            #pragma unroll
            for (int nf = 0; nf < 2; ++nf)
                acc[mf][nf] = __builtin_amdgcn_mfma_f32_16x16x32_bf16(aF[mf], bF[nf], acc[mf][nf], 0, 0, 0);
        PH_SYNC_OUT();
        // ---- phase 1: all frags ks1 ; vmcnt(0) at tile end (long flight)
        #pragma unroll
        for (int mf = 0; mf < 4; ++mf) aF[mf] = ldfrag(Ab, wm * 64 + mf * 16 + lr, 64 + kq, rs);
        #pragma unroll
        for (int nf = 0; nf < 2; ++nf) bF[nf] = ldfrag(Bb, wn * 32 + nf * 16 + lr, 64 + kq, rs);
        PH_SYNC_IN();
        #pragma unroll
        for (int mf = 0; mf < 4; ++mf)
            #pragma unroll
            for (int nf = 0; nf < 2; ++nf)
                acc[mf][nf] = __builtin_amdgcn_mfma_f32_16x16x32_bf16(aF[mf], bF[nf], acc[mf][nf], 0, 0, 0);
        __builtin_amdgcn_s_setprio(0);
        asm volatile("s_waitcnt vmcnt(0)" ::: "memory");
        __builtin_amdgcn_sched_barrier(0);
        __builtin_amdgcn_s_barrier();
    }

    const int r0 = (lane >> 4) << 2;
    float bv[2];
    #pragma unroll
    for (int nf = 0; nf < 2; ++nf) bv[nf] = bias[nt * 128 + wn * 32 + nf * 16 + lr];
    #pragma unroll
    for (int mf = 0; mf < 4; ++mf) {
        #pragma unroll
        for (int r = 0; r < 4; ++r) {
            const int row = mt * 128 + wm * 64 + mf * 16 + r0 + r;
            u16* orow = outH + (size_t)row * NH + nt * 128 + wn * 32 + lr;
            #pragma unroll
            for (int nf = 0; nf < 2; ++nf) {
                float v = acc[mf][nf][r] + bv[nf];
                orow[nf * 16] = f2bf(fmaxf(v, 0.0f));
            }
        }
    }
}

// ---------------- GEMM2 + L2 normalize (merged opinion+entity) ---------------
// 64x256 tile, BK=64, 256 thr (4 waves side-by-side in N), 80 KB LDS ->
// 2 blocks/CU. r9's 2-phase loop (stage both in phase 0). Unchanged.
#define G2_STAGE_A(t_, d_)                                                       \
  { _Pragma("unroll")                                                            \
    for (int i_ = 0; i_ < 2; ++i_)                                               \
      gload16((const char*)(ag + (size_t)(i_ * 32 + srow) * NH + (t_) * 64) + sswz, \
              (char*)&As2[d_][0] + i_ * 4096 + tid * 16); }
#define G2_STAGE_B(t_, d_)                                                       \
  { _Pragma("unroll")                                                            \
    for (int i_ = 0; i_ < 8; ++i_)                                               \
      gload16((const char*)(WT + (size_t)(i_ * 32 + srow) * NH + (t_) * 64) + sswz, \
              (char*)&Bs2[d_][0] + i_ * 4096 + tid * 16); }

__launch_bounds__(256, 2)
__global__ void gemm2norm_kernel(const u16* __restrict__ Hop, const u16* __restrict__ Hen,
                                 const u16* __restrict__ oW2T, const u16* __restrict__ eW2T,
                                 const float* __restrict__ ob2, const float* __restrict__ eb2,
                                 u16* __restrict__ opn, u16* __restrict__ eps) {
    __shared__ u16 As2[2][64 * 64];    // 16 KB (nsum aliased here after K-loop)
    __shared__ u16 Bs2[2][256 * 64];   // 64 KB
    float* nsum = (float*)&As2[0][0];  // [4][64]
    const int cpx = gridDim.x >> 3;
    const int wg = (blockIdx.x & 7) * cpx + (blockIdx.x >> 3);
    const bool isent = wg >= 512;                 // opinion: 512 blocks, entity: 64
    const int mt = isent ? wg - 512 : wg;
    const u16* Hin = isent ? Hen : Hop;
    const u16* WT = isent ? eW2T : oW2T;
    const float* bias = isent ? eb2 : ob2;
    u16* outZ = isent ? eps : opn;

    const int tid = threadIdx.x;
    const int lane = tid & 63;
    const int wn = tid >> 6;
    const int lr = lane & 15;
    const int kq = (lane >> 4) << 4;
    const int rs = (lr & 7) << 4;

    const int srow = tid >> 3;
    const int sswz = ((tid & 7) * 16) ^ ((srow & 7) << 4);
    const u16* ag = Hin + (size_t)(mt * 64) * NH;

    f32x4 acc[4][4] = {};

    G2_STAGE_A(0, 0);
    G2_STAGE_B(0, 0);
    asm volatile("s_waitcnt vmcnt(0)" ::: "memory");
    __builtin_amdgcn_s_barrier();

    for (int t = 0; t < NKT; ++t) {
        const int d = t & 1;
        const char* Ab = (const char*)&As2[d][0];
        const char* Bb = (const char*)&Bs2[d][0];
        bf16x8 aF[4], bF[4];
        // ---- phase 0: all frags ks0 ; stage A(t+1) AND B(t+1)
        #pragma unroll
        for (int mf = 0; mf < 4; ++mf) aF[mf] = ldfrag(Ab, mf * 16 + lr, kq, rs);
        #pragma unroll
        for (int nf = 0; nf < 4; ++nf) bF[nf] = ldfrag(Bb, wn * 64 + nf * 16 + lr, kq, rs);
        if (t < NKT - 1) { G2_STAGE_A(t + 1, d ^ 1); G2_STAGE_B(t + 1, d ^ 1); }
        PH_SYNC_IN();
        #pragma unroll
        for (int mf = 0; mf < 4; ++mf)
            #pragma unroll
            for (int nf = 0; nf < 4; ++nf)
                acc[mf][nf] = __builtin_amdgcn_mfma_f32_16x16x32_bf16(aF[mf], bF[nf], acc[mf][nf], 0, 0, 0);
        PH_SYNC_OUT();
        // ---- phase 1: all frags ks1 ; vmcnt(0) at tile end
        #pragma unroll
        for (int mf = 0; mf < 4; ++mf) aF[mf] = ldfrag(Ab, mf * 16 + lr, 64 + kq, rs);
        #pragma unroll
        for (int nf = 0; nf < 4; ++nf) bF[nf] = ldfrag(Bb, wn * 64 + nf * 16 + lr, 64 + kq, rs);
        PH_SYNC_IN();
        #pragma unroll
        for (int mf = 0; mf < 4; ++mf)
            #pragma unroll
            for (int nf = 0; nf < 4; ++nf)
                acc[mf][nf] = __builtin_amdgcn_mfma_f32_16x16x32_bf16(aF[mf], bF[nf], acc[mf][nf], 0, 0, 0);
        __builtin_amdgcn_s_setprio(0);
        asm volatile("s_waitcnt vmcnt(0)" ::: "memory");
        __builtin_amdgcn_sched_barrier(0);
        __builtin_amdgcn_s_barrier();
    }

    // bias + row sum-of-squares
    const int cc = wn * 64 + lr;
    #pragma unroll
    for (int nf = 0; nf < 4; ++nf) {
        const float bvv = bias[cc + nf * 16];
        #pragma unroll
        for (int mf = 0; mf < 4; ++mf)
            #pragma unroll
            for (int r = 0; r < 4; ++r)
                acc[mf][nf][r] += bvv;
    }
    float rsq[4][4];
    #pragma unroll
    for (int mf = 0; mf < 4; ++mf)
        #pragma unroll
        for (int r = 0; r < 4; ++r) {
            float s = 0.f;
            #pragma unroll
            for (int nf = 0; nf < 4; ++nf) s += acc[mf][nf][r] * acc[mf][nf][r];
            rsq[mf][r] = s;
        }
    #pragma unroll
    for (int mask = 1; mask <= 8; mask <<= 1)
        #pragma unroll
        for (int mf = 0; mf < 4; ++mf)
            #pragma unroll
            for (int r = 0; r < 4; ++r)
                rsq[mf][r] += __shfl_xor(rsq[mf][r], mask);
    const int r0 = (lane >> 4) << 2;
    __syncthreads();                    // As2 reads all done; safe to alias nsum
    if (lr == 0) {
        #pragma unroll
        for (int mf = 0; mf < 4; ++mf)
            #pragma unroll
            for (int r = 0; r < 4; ++r)
                nsum[wn * 64 + mf * 16 + r0 + r] = rsq[mf][r];
    }
    __syncthreads();
    #pragma unroll
    for (int mf = 0; mf < 4; ++mf) {
        #pragma unroll
        for (int r = 0; r < 4; ++r) {
            const int row = mf * 16 + r0 + r;
            const float tot = nsum[row] + nsum[64 + row] + nsum[128 + row] + nsum[192 + row];
            const float inv = 1.0f / fmaxf(sqrtf(tot), 1e-12f);
            u16* orow = outZ + (size_t)(mt * 64 + row) * NP + cc;
            #pragma unroll
            for (int nf = 0; nf < 4; ++nf)
                orow[nf * 16] = f2bf(acc[mf][nf][r] * inv);
        }
    }
}

// ---------------- score: 2 blocks per batch; wave-parallel single-pass softmax
__launch_bounds__(256)
__global__ void score_kernel(const u16* __restrict__ epsel, const u16* __restrict__ opn,
                             const int* __restrict__ pairs, float* __restrict__ partials) {
    __shared__ u16 Asx[16][264];
    __shared__ float simbuf[16][257];
    __shared__ float red[16];
    const int b = blockIdx.x >> 1;
    const int half = blockIdx.x & 1;
    const int rbase = half * 16;
    const int tid = threadIdx.x;
    const int lane = tid & 63;
    const int w = tid >> 6;
    {
        const int row = tid >> 4, q = tid & 15;   // 16 threads per row, 16 elems each
        const u16* p = epsel + ((size_t)(b * NT + rbase + row)) * NP + q * 16;
        *(uint4*)&Asx[row][q * 16 + 0] = *(const uint4*)(p + 0);
        *(uint4*)&Asx[row][q * 16 + 8] = *(const uint4*)(p + 8);
    }
    __syncthreads();
    f32x4 acc[4] = {};
    const u16* opb = opn + (size_t)b * NO * NP;
    const int kq = (lane >> 4) << 3;
    for (int kk = 0; kk < NP; kk += 32) {
        bf16x8 af = *(const bf16x8*)&Asx[lane & 15][kk + kq];
        #pragma unroll
        for (int n = 0; n < 4; ++n) {
            bf16x8 bfr = *(const bf16x8*)(opb + (size_t)(w * 64 + n * 16 + (lane & 15)) * NP + kk + kq);
            acc[n] = __builtin_amdgcn_mfma_f32_16x16x32_bf16(af, bfr, acc[n], 0, 0, 0);
        }
    }
    const int r0 = (lane >> 4) << 2;
    #pragma unroll
    for (int n = 0; n < 4; ++n)
        #pragma unroll
        for (int r = 0; r < 4; ++r)
            simbuf[r0 + r][w * 64 + n * 16 + (lane & 15)] = acc[n][r] * INV_TEMP;
    __syncthreads();
    {
        const int row = tid >> 4, sub = tid & 15;
        float s = 0.f;
        #pragma unroll 4
        for (int j = sub; j < NO; j += 16) s += __expf(simbuf[row][j]);
        s += __shfl_xor(s, 1);
        s += __shfl_xor(s, 2);
        s += __shfl_xor(s, 4);
        s += __shfl_xor(s, 8);
        if (sub == 0) {
            const int o = pairs[(b * NT + rbase + row) * 2 + 1];
            red[row] = logf(s) - simbuf[row][o];
        }
    }
    __syncthreads();
    if (tid == 0) {
        float s = 0.f;
        #pragma unroll
        for (int t = 0; t < 16; ++t) s += red[t];
        partials[blockIdx.x] = s;
    }
}

__global__ void reduce_kernel(const float* __restrict__ partials, float* __restrict__ out) {
    const int tid = threadIdx.x;              // 256
    float v = partials[tid];
    #pragma unroll
    for (int m = 1; m <= 32; m <<= 1) v += __shfl_xor(v, m);
    __shared__ float s[4];
    if ((tid & 63) == 0) s[tid >> 6] = v;
    __syncthreads();
    if (tid == 0) out[0] = (s[0] + s[1] + s[2] + s[3]) / (float)(BATCH * NT);
}

extern "C" void kernel_launch(void* const* d_in, const int* in_sizes, int n_in,
                              void* d_out, int out_size, void* d_ws, size_t ws_size,
                              hipStream_t stream) {
    const float* ent  = (const float*)d_in[0];
    const float* opi  = (const float*)d_in[1];
    const int*   prs  = (const int*)d_in[2];
    const float* eW1  = (const float*)d_in[3];
    const float* eb1  = (const float*)d_in[4];
    const float* eW2  = (const float*)d_in[5];
    const float* eb2  = (const float*)d_in[6];
    const float* oW1  = (const float*)d_in[7];
    const float* ob1  = (const float*)d_in[8];
    const float* oW2  = (const float*)d_in[9];
    const float* ob2  = (const float*)d_in[10];
    float* out = (float*)d_out;

    char* ws = (char*)d_ws;
    size_t off = 0;
    auto alloc = [&](size_t bytes) {
        void* p = ws + off;
        off += (bytes + 255) & ~(size_t)255;
        return p;
    };
    u16* oW1T = (u16*)alloc((size_t)NH * NH * 2);
    u16* eW1T = (u16*)alloc((size_t)NH * NH * 2);
    u16* oW2T = (u16*)alloc((size_t)NP * NH * 2);
    u16* eW2T = (u16*)alloc((size_t)NP * NH * 2);
    u16* A_op = (u16*)alloc((size_t)BATCH * NO * NH * 2);
    u16* A_en = (u16*)alloc((size_t)BATCH * NT * NH * 2);
    u16* h_op = (u16*)alloc((size_t)BATCH * NO * NH * 2);
    u16* h_en = (u16*)alloc((size_t)BATCH * NT * NH * 2);
    u16* op_n = (u16*)alloc((size_t)BATCH * NO * NP * 2);
    u16* ep_s = (u16*)alloc((size_t)BATCH * NT * NP * 2);
    float* partials = (float*)alloc(2 * BATCH * sizeof(float));
    (void)ws_size; (void)in_sizes; (void)n_in; (void)out_size;

    // merged prep: activations bf16 (+ entity gather) + 4 weight transposes
    prep_kernel<<<PREP_TOTAL, 256, 0, stream>>>(opi, ent, prs, oW1, eW1, oW2, eW2,
                                                A_op, A_en, oW1T, eW1T, oW2T, eW2T);

    // encoder layer 1 (relu): opinion 1536 + entity 192 = 1728 blocks (%8==0)
    gemm1_kernel<<<1728, 512, 0, stream>>>(A_op, A_en, oW1T, eW1T, ob1, eb1, h_op, h_en);

    // encoder layer 2 + normalize: opinion 512 + entity 64 = 576 blocks (%8==0)
    gemm2norm_kernel<<<576, 256, 0, stream>>>(h_op, h_en, oW2T, eW2T, ob2, eb2, op_n, ep_s);

    // similarity rows + InfoNCE partials (2 blocks per batch)
    score_kernel<<<2 * BATCH, 256, 0, stream>>>(ep_s, op_n, prs, partials);
    reduce_kernel<<<1, 256, 0, stream>>>(partials, out);
}